// Round 10
// baseline (164.686 us; speedup 1.0000x reference)
//
#include <hip/hip_runtime.h>
#include <hip/hip_bf16.h>

#define N_NODES 10000
#define KP      10240   // K padded; xwt pad slabs are ZERO
#define F       128
#define SPLITS  8
#define KSPLIT  1280    // KP / SPLITS
#define BK      64
#define TPS     20      // tiles per split
#define BM      128
#define MBLK    79      // ceil(10000/128)
#define PROWS   10112   // MBLK*128

typedef float  f32x4  __attribute__((ext_vector_type(4)));
typedef short  bf16x8 __attribute__((ext_vector_type(8)));
typedef short  s16x8  __attribute__((ext_vector_type(8)));

static __device__ __forceinline__ unsigned short f2bf(float f) {
    unsigned u = __builtin_bit_cast(unsigned, f);
    u += 0x7FFFu + ((u >> 16) & 1u);
    return (unsigned short)(u >> 16);
}

static __device__ __forceinline__ bf16x8 pack8(f32x4 lo, f32x4 hi) {
    bf16x8 r;
    r[0] = (short)f2bf(lo[0]); r[1] = (short)f2bf(lo[1]);
    r[2] = (short)f2bf(lo[2]); r[3] = (short)f2bf(lo[3]);
    r[4] = (short)f2bf(hi[0]); r[5] = (short)f2bf(hi[1]);
    r[6] = (short)f2bf(hi[2]); r[7] = (short)f2bf(hi[3]);
    return r;
}

// ---------------------------------------------------------------------------
// Kernel 1: xwt = (X @ W1)^T bf16 in MFMA-native tiles (R7 layout, unswizzled):
//   [kc(320)][ct(8)][c(16)][k(32)] ; each 16c x 32k tile = 1KB contiguous.
// grid 640 x 256; pad k (nodes >= 10000) -> 0.
// ---------------------------------------------------------------------------
__global__ __launch_bounds__(256) void k_xw(const float* __restrict__ x,
                                            const float* __restrict__ W1,
                                            unsigned short* __restrict__ xwt) {
    __shared__ float xs[16][128];
    __shared__ unsigned short ts[16][136];
    const int t  = threadIdx.x;
    const int nb = blockIdx.x * 16;

    #pragma unroll
    for (int i = 0; i < 2; ++i) {
        int idx = t + i * 256;
        int n   = idx >> 5;
        int c4  = idx & 31;
        int gn  = nb + n; if (gn > N_NODES - 1) gn = N_NODES - 1;
        f32x4 v = *reinterpret_cast<const f32x4*>(x + (size_t)gn * F + c4 * 4);
        *reinterpret_cast<f32x4*>(&xs[n][c4 * 4]) = v;
    }
    __syncthreads();

    const int f  = t & 127;
    const int ng = t >> 7;
    float acc[8] = {0.f, 0.f, 0.f, 0.f, 0.f, 0.f, 0.f, 0.f};

    for (int c4 = 0; c4 < 32; ++c4) {
        float w0 = W1[(4 * c4 + 0) * F + f];
        float w1 = W1[(4 * c4 + 1) * F + f];
        float w2 = W1[(4 * c4 + 2) * F + f];
        float w3 = W1[(4 * c4 + 3) * F + f];
        #pragma unroll
        for (int i = 0; i < 8; ++i) {
            f32x4 xv = *reinterpret_cast<const f32x4*>(&xs[ng * 8 + i][c4 * 4]);
            acc[i] = fmaf(xv.x, w0, fmaf(xv.y, w1, fmaf(xv.z, w2, fmaf(xv.w, w3, acc[i]))));
        }
    }

    #pragma unroll
    for (int i = 0; i < 8; ++i) ts[ng * 8 + i][f] = f2bf(acc[i]);
    __syncthreads();

    {
        const int col = t >> 1, half = t & 1;
        s16x8 v8;
        #pragma unroll
        for (int i = 0; i < 8; ++i) {
            int n = half * 8 + i;
            v8[i] = (nb + n < N_NODES) ? (short)ts[n][col] : (short)0;
        }
        const int kc = nb >> 5, khalf = (nb >> 4) & 1;
        size_t off = (size_t)kc * 4096 + (size_t)(col >> 4) * 512
                   + (size_t)(col & 15) * 32 + khalf * 16 + half * 8;
        *reinterpret_cast<s16x8*>(xwt + off) = v8;
    }
}

// ---------------------------------------------------------------------------
// Kernel 2: partial GEMM, split-K. grid (79 mblocks x 8 splits) x 512 thr.
// Block: 128 rows x 128 cols x 1280 k. Wave (mq=w>>2, cq=w&3): 64x32 subtile.
// A: 512B-per-row DRAM visits, pair-loaded into a ring-4 LDS (4x16KB,
//    XOR-swizzled, write-ahead-2 / load-ahead-4). B: L2 -> registers direct
//    (4 frags/tile from tiled xwt, reload-after-use). lgkmcnt-only barrier.
// ---------------------------------------------------------------------------
#define MFMA(a, b, c) __builtin_amdgcn_mfma_f32_16x16x32_bf16(a, b, c, 0, 0, 0)

#define SYNC() do { asm volatile("s_waitcnt lgkmcnt(0)" ::: "memory"); \
                    __builtin_amdgcn_s_barrier(); } while (0)

__global__ __launch_bounds__(512, 4) void k_gcn(const float* __restrict__ A,
                                                const unsigned short* __restrict__ xwt,
                                                float* __restrict__ P) {
    __shared__ __align__(16) unsigned char As[4][16384];   // 64 KB ring

    const int t    = threadIdx.x;
    const int w    = t >> 6;
    const int lane = t & 63;
    const int l16  = lane & 15;
    const int g    = lane >> 4;
    const int mq   = w >> 2;         // 0..1 : 64-row half
    const int cq   = w & 3;          // 0..3 : 32-col quarter
    const int mb    = blockIdx.x % MBLK;
    const int split = blockIdx.x / MBLK;
    const int rbase = mb * BM;
    const int k0    = split * KSPLIT;

    // ---- A staging: thread t -> row (t>>2), 128B chunk (t&3) of a 512B pair ----
    const int sr = t >> 2, c8 = t & 3;
    int arow = rbase + sr; if (arow > N_NODES - 1) arow = N_NODES - 1;
    const size_t abase0 = (size_t)arow * N_NODES + k0 + c8 * 32;
    const size_t alim   = (size_t)N_NODES * N_NODES - 32;   // reads 32 floats

    const unsigned char* const xb  = reinterpret_cast<const unsigned char*>(xwt);
    unsigned char* const Asb = &As[0][0];

    // ---- fragment read byte offsets ----
    int ar00, ar01, ar10, ar11, ar20, ar21, ar30, ar31;   // ar[mf][kf]
    {
        int r0 = mq * 64 +  0 + l16, r1 = mq * 64 + 16 + l16;
        int r2 = mq * 64 + 32 + l16, r3 = mq * 64 + 48 + l16;
        ar00 = r0 * 128 + ((0 + g) ^ (r0 & 7)) * 16;  ar01 = r0 * 128 + ((4 + g) ^ (r0 & 7)) * 16;
        ar10 = r1 * 128 + ((0 + g) ^ (r1 & 7)) * 16;  ar11 = r1 * 128 + ((4 + g) ^ (r1 & 7)) * 16;
        ar20 = r2 * 128 + ((0 + g) ^ (r2 & 7)) * 16;  ar21 = r2 * 128 + ((4 + g) ^ (r2 & 7)) * 16;
        ar30 = r3 * 128 + ((0 + g) ^ (r3 & 7)) * 16;  ar31 = r3 * 128 + ((4 + g) ^ (r3 & 7)) * 16;
    }
    const int bco = cq * 2048 + l16 * 64 + g * 16;   // within-slab byte offset

    f32x4 acc00 = {0.f,0.f,0.f,0.f}, acc01 = acc00, acc10 = acc00, acc11 = acc00;
    f32x4 acc20 = acc00, acc21 = acc00, acc30 = acc00, acc31 = acc00;

    f32x4 la0, la1, la2, la3, la4, la5, la6, la7;   // A pair stage (128B)
    bf16x8 b0, b1, b2, b3;                          // B frags for current tile

#define LOADA(tp) do {                                                           \
    size_t _ao = abase0 + (size_t)(tp) * BK;                                     \
    if (_ao > alim) _ao = alim;                                                  \
    const f32x4* _p = reinterpret_cast<const f32x4*>(A + _ao);                   \
    la0 = _p[0]; la1 = _p[1]; la2 = _p[2]; la3 = _p[3];                          \
    la4 = _p[4]; la5 = _p[5]; la6 = _p[6]; la7 = _p[7];                          \
} while (0)

#define WRITEA(s0, s1) do {                                                      \
    int _slot = (c8 < 2) ? (s0) : (s1);                                          \
    int _u0   = (c8 & 1) * 4;                                                    \
    unsigned char* _pp = Asb + _slot * 16384 + sr * 128;                         \
    *reinterpret_cast<bf16x8*>(_pp + ((_u0 + 0) ^ (sr & 7)) * 16) = pack8(la0, la1); \
    *reinterpret_cast<bf16x8*>(_pp + ((_u0 + 1) ^ (sr & 7)) * 16) = pack8(la2, la3); \
    *reinterpret_cast<bf16x8*>(_pp + ((_u0 + 2) ^ (sr & 7)) * 16) = pack8(la4, la5); \
    *reinterpret_cast<bf16x8*>(_pp + ((_u0 + 3) ^ (sr & 7)) * 16) = pack8(la6, la7); \
} while (0)

#define LOADB(tile) do {                                                         \
    const unsigned char* _s = xb + (size_t)(split * 40 + 2 * (tile)) * 8192 + bco; \
    b0 = *reinterpret_cast<const bf16x8*>(_s);                                   \
    b1 = *reinterpret_cast<const bf16x8*>(_s + 1024);                            \
    b2 = *reinterpret_cast<const bf16x8*>(_s + 8192);                            \
    b3 = *reinterpret_cast<const bf16x8*>(_s + 8192 + 1024);                     \
} while (0)

#define COMPUTE(slot) do {                                                       \
    const unsigned char* _as = Asb + (slot) * 16384;                             \
    bf16x8 _a0 = *reinterpret_cast<const bf16x8*>(_as + ar00);                   \
    bf16x8 _a1 = *reinterpret_cast<const bf16x8*>(_as + ar10);                   \
    bf16x8 _a2 = *reinterpret_cast<const bf16x8*>(_as + ar20);                   \
    bf16x8 _a3 = *reinterpret_cast<const bf16x8*>(_as + ar30);                   \
    acc00 = MFMA(_a0, b0, acc00); acc01 = MFMA(_a0, b1, acc01);                  \
    acc10 = MFMA(_a1, b0, acc10); acc11 = MFMA(_a1, b1, acc11);                  \
    acc20 = MFMA(_a2, b0, acc20); acc21 = MFMA(_a2, b1, acc21);                  \
    acc30 = MFMA(_a3, b0, acc30); acc31 = MFMA(_a3, b1, acc31);                  \
    _a0 = *reinterpret_cast<const bf16x8*>(_as + ar01);                          \
    _a1 = *reinterpret_cast<const bf16x8*>(_as + ar11);                          \
    _a2 = *reinterpret_cast<const bf16x8*>(_as + ar21);                          \
    _a3 = *reinterpret_cast<const bf16x8*>(_as + ar31);                          \
    acc00 = MFMA(_a0, b2, acc00); acc01 = MFMA(_a0, b3, acc01);                  \
    acc10 = MFMA(_a1, b2, acc10); acc11 = MFMA(_a1, b3, acc11);                  \
    acc20 = MFMA(_a2, b2, acc20); acc21 = MFMA(_a2, b3, acc21);                  \
    acc30 = MFMA(_a3, b2, acc30); acc31 = MFMA(_a3, b3, acc31);                  \
} while (0)

    // prologue: slots 0,1 written; pair (2,3) in regs; B tile 0 in regs
    LOADA(0); WRITEA(0, 1);
    LOADA(2);
    LOADB(0);
    SYNC();

    for (int tile = 0; tile < TPS; ++tile) {
        if ((tile & 1) == 0) {
            if (tile + 2 < TPS) WRITEA((tile + 2) & 3, (tile + 3) & 3);
            if (tile + 4 < TPS) LOADA(tile + 4);
        }
        COMPUTE(tile & 3);
        if (tile + 1 < TPS) LOADB(tile + 1);
        SYNC();
    }

    // ---- write f32 partials ----
    {
        float* Pp = P + ((size_t)split * PROWS + rbase) * F;
        #pragma unroll
        for (int e = 0; e < 4; ++e) {
            Pp[(size_t)(mq * 64 +  0 + g * 4 + e) * F + cq * 32 +      l16] = acc00[e];
            Pp[(size_t)(mq * 64 +  0 + g * 4 + e) * F + cq * 32 + 16 + l16] = acc01[e];
            Pp[(size_t)(mq * 64 + 16 + g * 4 + e) * F + cq * 32 +      l16] = acc10[e];
            Pp[(size_t)(mq * 64 + 16 + g * 4 + e) * F + cq * 32 + 16 + l16] = acc11[e];
            Pp[(size_t)(mq * 64 + 32 + g * 4 + e) * F + cq * 32 +      l16] = acc20[e];
            Pp[(size_t)(mq * 64 + 32 + g * 4 + e) * F + cq * 32 + 16 + l16] = acc21[e];
            Pp[(size_t)(mq * 64 + 48 + g * 4 + e) * F + cq * 32 +      l16] = acc30[e];
            Pp[(size_t)(mq * 64 + 48 + g * 4 + e) * F + cq * 32 + 16 + l16] = acc31[e];
        }
    }
#undef LOADA
#undef WRITEA
#undef LOADB
#undef COMPUTE
}

// ---------------------------------------------------------------------------
// Kernel 3: out[r] = relu(sum_s P[s][r][:] + b1) . W2 + b2. grid 5000 x 256.
// ---------------------------------------------------------------------------
__global__ __launch_bounds__(256) void k_red(const float* __restrict__ P,
                                             const float* __restrict__ b1,
                                             const float* __restrict__ W2,
                                             const float* __restrict__ b2,
                                             float* __restrict__ out) {
    __shared__ float sred[4];
    const int t   = threadIdx.x;
    const int row = blockIdx.x * 2 + (t >> 7);
    const int c   = t & 127;

    float v = 0.f;
    #pragma unroll
    for (int s = 0; s < SPLITS; ++s)
        v += P[((size_t)s * PROWS + row) * F + c];
    v = fmaxf(v + b1[c], 0.f) * W2[c];

    v += __shfl_xor(v, 1);
    v += __shfl_xor(v, 2);
    v += __shfl_xor(v, 4);
    v += __shfl_xor(v, 8);
    v += __shfl_xor(v, 16);
    v += __shfl_xor(v, 32);
    if ((t & 63) == 0) sred[t >> 6] = v;
    __syncthreads();
    if (t < 2) out[blockIdx.x * 2 + t] = sred[t * 2] + sred[t * 2 + 1] + b2[0];
}

extern "C" void kernel_launch(void* const* d_in, const int* in_sizes, int n_in,
                              void* d_out, int out_size, void* d_ws, size_t ws_size,
                              hipStream_t stream) {
    const float* x  = (const float*)d_in[0];
    const float* a  = (const float*)d_in[1];
    const float* W1 = (const float*)d_in[2];
    const float* b1 = (const float*)d_in[3];
    const float* W2 = (const float*)d_in[4];
    const float* b2 = (const float*)d_in[5];
    float* out = (float*)d_out;

    unsigned short* xwt = (unsigned short*)d_ws;                  // 2.62 MB tiled
    float* P = (float*)((char*)d_ws + (size_t)(32 << 20));        // 8x10112x128 f32

    k_xw<<<640, 256, 0, stream>>>(x, W1, xwt);
    k_gcn<<<MBLK * SPLITS, 512, 0, stream>>>(a, xwt, P);
    k_red<<<5000, 256, 0, stream>>>(P, b1, W2, b2, out);
}